// Round 10
// baseline (168.430 us; speedup 1.0000x reference)
//
#include <hip/hip_runtime.h>
#include <hip/hip_bf16.h>

#define NSENT 4000
#define LSEQ  128
#define VEC   50
#define WSTR  52      // bf16 word-emb row stride (shorts): 50 real + 2 zero, 104 B (8B-aligned)
#define NVOCAB 50002
#define POS   5
#define EMBD  60      // VEC + 2*POS
#define HIDD  230
#define HSTR  232     // padded channel stride for H / hS
#define NBAG  500
#define NREL  25
#define BAGSZ 8
#define NTILEP 16     // padded N-tile count (15 real, tile 15 = zeros)
#define KSTEPS 6      // K = 192 (3 taps * 64 e-slots), 6 MFMA K-steps of 32
#define ESTR  72      // LDS row stride in bf16 shorts (144 B; 9x16B units -> uniform banks)
#define SLOTS 130     // l+1 shift; rows 0/129 are SAME-pad zeros
#define SSTR  (SLOTS * ESTR)   // per-sentence LDS slab (shorts)
#define WBLOCKS 2540  // prep: wbf part = NVOCAB*13 uint2-threads / 256

// e-slot mapping (A and B MUST agree):
//   e 0..49  = wemb dims 0..49      (e50,51 = 0)
//   e 52..55 = p1 dims 0..3
//   e 56..59 = p2 dims 0..3
//   e 60     = p1 dim 4, e61 = 0
//   e 62     = p2 dim 4, e63 = 0
typedef __attribute__((ext_vector_type(8))) short short8;   // 8 bf16 = 4 VGPRs
typedef __attribute__((ext_vector_type(4))) float f32x4;

__device__ __forceinline__ unsigned short f2bf(float f) {
    union { float f; unsigned u; } v; v.f = f;
    unsigned u = v.u + 0x7FFF + ((v.u >> 16) & 1);   // RNE
    return (unsigned short)(u >> 16);
}

// packed f32x2 -> bf16x2 (v_cvt_pk_bf16_f32 on gfx950), low short = first arg
__device__ __forceinline__ unsigned pk(float a, float b) {
    __hip_bfloat162 h = __float22bfloat162_rn(float2{a, b});
    union { __hip_bfloat162 h; unsigned u; } c; c.h = h;
    return c.u;
}

// ---- merged prep: wbf table cvt (blocks < WBLOCKS) + Bfrag build (rest) ----
__global__ __launch_bounds__(256) void prep(const float* __restrict__ conv_w,
                                            const float* __restrict__ wemb,
                                            unsigned short* __restrict__ Bfrag,
                                            unsigned short* __restrict__ wbf) {
    int bid = blockIdx.x;
    if (bid < WBLOCKS) {
        int idx = bid * 256 + threadIdx.x;        // one uint2 (4 shorts) of wbf
        if (idx < NVOCAB * 13) {
            int r = idx / 13, cj = (idx % 13) * 4;
            const float* src = wemb + (size_t)r * VEC + cj;
            float2 a = *(const float2*)src;
            float2 b = (cj < 48) ? *(const float2*)(src + 2) : float2{0.f, 0.f};
            uint2 v; v.x = pk(a.x, a.y); v.y = pk(b.x, b.y);
            *(uint2*)(wbf + (size_t)r * WSTR + cj) = v;
        }
    } else {
        int idx = (bid - WBLOCKS) * 256 + threadIdx.x;
        if (idx >= NTILEP * KSTEPS * 64 * 8) return;
        int j    = idx & 7;
        int lane = (idx >> 3) & 63;
        int t    = idx >> 9;
        int ks   = t % KSTEPS;
        int nt   = t / KSTEPS;
        int c    = nt * 16 + (lane & 15);
        int klin = ks * 32 + (lane >> 4) * 8 + j;
        int tap  = klin >> 6;
        int e    = klin & 63;
        float v  = 0.f;
        if (c < HIDD) {
            int eidx = -1;
            if (e < 50)                 eidx = e;             // wemb dims
            else if (e >= 52 && e < 56) eidx = 50 + (e - 52); // p1[0..3]
            else if (e >= 56 && e < 60) eidx = 55 + (e - 56); // p2[0..3]
            else if (e == 60)           eidx = 54;            // p1[4]
            else if (e == 62)           eidx = 59;            // p2[4]
            if (eidx >= 0) v = conv_w[(c * EMBD + eidx) * 3 + tap];
        }
        Bfrag[idx] = f2bf(v);
    }
}

// ---- standalone prep_b for the fallback path (no wbf region in ws) ----
__global__ __launch_bounds__(256) void prep_b(const float* __restrict__ conv_w,
                                              unsigned short* __restrict__ Bfrag) {
    int idx = blockIdx.x * 256 + threadIdx.x;
    if (idx >= NTILEP * KSTEPS * 64 * 8) return;
    int j    = idx & 7;
    int lane = (idx >> 3) & 63;
    int t    = idx >> 9;
    int ks   = t % KSTEPS;
    int nt   = t / KSTEPS;
    int c    = nt * 16 + (lane & 15);
    int klin = ks * 32 + (lane >> 4) * 8 + j;
    int tap  = klin >> 6;
    int e    = klin & 63;
    float v  = 0.f;
    if (c < HIDD) {
        int eidx = -1;
        if (e < 50)                 eidx = e;
        else if (e >= 52 && e < 56) eidx = 50 + (e - 52);
        else if (e >= 56 && e < 60) eidx = 55 + (e - 56);
        else if (e == 60)           eidx = 54;
        else if (e == 62)           eidx = 59;
        if (eidx >= 0) v = conv_w[(c * EMBD + eidx) * 3 + tap];
    }
    Bfrag[idx] = f2bf(v);
}

// ---- gather one sentence (prologue only); R7-proven code ----
__device__ __forceinline__ void gather_one(
    unsigned short* __restrict__ slab, int s, int tid,
    const int* __restrict__ xS, const int* __restrict__ p1S, const int* __restrict__ p2S,
    const unsigned short* __restrict__ wbf,
    const float* __restrict__ p1emb, const float* __restrict__ p2emb)
{
    #pragma unroll
    for (int it = 0; it < (LSEQ * 16) / 512; ++it) {
        int i = tid + it * 512;
        int l = i >> 4, j = i & 15;
        int li = s * LSEQ + l;
        unsigned short* dst = slab + (l + 1) * ESTR;
        uint2 v;
        if (j < 13) {                 // shorts 4j..4j+3 of bf16 row (j=12 brings the 2 zeros)
            v = *(const uint2*)(wbf + (size_t)xS[li] * WSTR + j * 4);
        } else if (j == 13) {         // p1[0..3] -> e52..55
            const float* p = p1emb + p1S[li] * POS;
            v.x = pk(p[0], p[1]); v.y = pk(p[2], p[3]);
        } else if (j == 14) {         // p2[0..3] -> e56..59
            const float* p = p2emb + p2S[li] * POS;
            v.x = pk(p[0], p[1]); v.y = pk(p[2], p[3]);
        } else {                      // tails -> e60..63
            float a = p1emb[p1S[li] * POS + 4];
            float b = p2emb[p2S[li] * POS + 4];
            v.x = pk(a, 0.f); v.y = pk(b, 0.f);
        }
        *(uint2*)(dst + (j < 13 ? j * 4 : 52 + (j - 13) * 4)) = v;
    }
}

// ---- compute one sentence: PROVEN R5/R7 inner loop; output -> LDS hrow ----
__device__ __forceinline__ void compute_one_lds(
    const unsigned short* __restrict__ eb, const short8 Bw[2][KSTEPS],
    int m, int quad, int nt0, int lane,
    const float* __restrict__ conv_b, float* __restrict__ hrow)
{
    float maxv[2][4];
    #pragma unroll
    for (int t = 0; t < 2; ++t)
        #pragma unroll
        for (int r = 0; r < 4; ++r) maxv[t][r] = -1e30f;

    #pragma unroll
    for (int mt = 0; mt < 8; ++mt) {
        short8 A[KSTEPS];
        #pragma unroll
        for (int ks = 0; ks < KSTEPS; ++ks) {
            int tap = ks >> 1;
            int col = (ks & 1) * 32 + quad * 8;
            int row = mt * 16 + m + tap;        // slot (l+tap), +1 shift folded in
            A[ks] = *(const short8*)(eb + row * ESTR + col);
        }
        f32x4 acc[2];
        #pragma unroll
        for (int t = 0; t < 2; ++t) acc[t] = (f32x4){0.f, 0.f, 0.f, 0.f};
        #pragma unroll
        for (int ks = 0; ks < KSTEPS; ++ks)
            #pragma unroll
            for (int t = 0; t < 2; ++t)
                acc[t] = __builtin_amdgcn_mfma_f32_16x16x32_bf16(A[ks], Bw[t][ks], acc[t], 0, 0, 0);
        #pragma unroll
        for (int t = 0; t < 2; ++t)
            #pragma unroll
            for (int r = 0; r < 4; ++r)
                maxv[t][r] = fmaxf(maxv[t][r], acc[t][r]);
    }

    #pragma unroll
    for (int t = 0; t < 2; ++t) {
        float v = fmaxf(fmaxf(maxv[t][0], maxv[t][1]),
                        fmaxf(maxv[t][2], maxv[t][3]));
        v = fmaxf(v, __shfl_xor(v, 16));
        v = fmaxf(v, __shfl_xor(v, 32));
        int c = (nt0 + t) * 16 + lane;
        if (lane < 16 && c < HIDD)
            hrow[c] = fmaxf(v + conv_b[c], 0.f);
    }
}

// ---- Kernel 2: ONE BLOCK = ONE BAG, T14 split-gather pipeline (v2) ----
// R9 structure (149.2us total) with ONE change: phase L is now PURE LOAD
// ISSUE for ALL 16 lane roles. R9 converted pos lanes (jj>=13) with pk
// inside phase L; since every wave contains all 16 roles, every wave stalled
// on the pos load->pk dependent chain (partial vmcnt wait) BEFORE compute.
// Now pos lanes hold RAW f32 bits in gv/gv2 (+8 VGPR, live only L->W; pos
// rows are 20B-strided so loads stay scalar dwords, count unchanged) and all
// pk conversions move to phase W, where the loads landed long ago under the
// MFMA stream. Phase L contains zero waitcnt-consuming instructions.
// TRIPWIRE: VGPR>96 or WRITE_SIZE spike => spill => revert to R9.
// LDS: 37440 (2 slabs) + 12288 (idx) + 7424 (hS) + 960 (lgS/repS) = 58.1 KB.
__global__ __launch_bounds__(512, 4) void encoder_bag(
    const int*   __restrict__ X,  const int* __restrict__ P1, const int* __restrict__ P2,
    const unsigned short* __restrict__ wbf,
    const float* __restrict__ p1emb, const float* __restrict__ p2emb,
    const unsigned short* __restrict__ Bfrag, const float* __restrict__ conv_b,
    const int* __restrict__ relation, const int* __restrict__ scope,
    const float* __restrict__ rel_w, const float* __restrict__ rel_b,
    float* __restrict__ out)
{
    __shared__ unsigned short embS[2 * SSTR];            // 2 alternating slabs
    __shared__ int xS[BAGSZ * LSEQ], p1S[BAGSZ * LSEQ], p2S[BAGSZ * LSEQ];
    __shared__ float hS[BAGSZ][HSTR];                    // encoder outputs
    __shared__ float lgS[BAGSZ];                         // bag logits
    __shared__ float repS[HSTR];                         // bag representation
    const int b = blockIdx.x, tid = threadIdx.x;
    const int lane = tid & 63;
    const int wave = __builtin_amdgcn_readfirstlane(tid >> 6);
    const int nt0  = wave * 2;
    const int m    = lane & 15;
    const int quad = lane >> 4;
    const int jj   = tid & 15;     // gather column role, constant per thread
    const int l0   = tid >> 4;     // gather base token, +32 per iteration

    // ---- this wave's B fragments -> registers (48 VGPRs), issued first
    short8 Bw[2][KSTEPS];
    #pragma unroll
    for (int t = 0; t < 2; ++t)
        #pragma unroll
        for (int ks = 0; ks < KSTEPS; ++ks)
            Bw[t][ks] = *(const short8*)(Bfrag + ((size_t)((nt0 + t) * KSTEPS + ks) * 64 + lane) * 8);

    // ---- stage index rows for all 8 sentences (3072 coalesced ints)
    #pragma unroll
    for (int it = 0; it < 6; ++it) {
        int i = tid + it * 512;
        int arr = i >> 10, off = i & 1023;
        const int* src = (arr == 0) ? X : (arr == 1) ? P1 : P2;
        int v = src[(size_t)b * (BAGSZ * LSEQ) + off];
        int* dst = (arr == 0) ? xS : (arr == 1) ? p1S : p2S;
        dst[off] = v;
    }
    // ---- zero SAME-pad rows of both slabs (e-slots 0..63)
    if (tid < 128) {
        int sb = tid >> 6;
        int r = (tid & 32) ? (SLOTS - 1) : 0;
        *(unsigned*)(embS + sb * SSTR + r * ESTR + (tid & 31) * 2) = 0u;
    }
    __syncthreads();

    // ---- pipeline: gather(0); then per round: loadL(s+1); compute(s); writeW(s+1)
    gather_one(embS, 0, tid, xS, p1S, p2S, wbf, p1emb, p2emb);
    __syncthreads();

    #pragma unroll 1
    for (int s = 0; s < BAGSZ; ++s) {
        const int sn = s + 1;
        const bool do_g = (sn < BAGSZ);
        uint2 gv[4], gv2[4];                           // statically indexed (unrolled)

        // ---- phase L: PURE load issue, no conversions, no waits
        if (do_g) {
            if (jj < 13) {
                #pragma unroll
                for (int it = 0; it < 4; ++it) {
                    int li = sn * LSEQ + l0 + it * 32;
                    gv[it] = *(const uint2*)(wbf + (size_t)xS[li] * WSTR + jj * 4);
                }
            } else if (jj == 13) {
                #pragma unroll
                for (int it = 0; it < 4; ++it) {
                    const float* p = p1emb + p1S[sn * LSEQ + l0 + it * 32] * POS;
                    gv[it].x  = __float_as_uint(p[0]); gv[it].y  = __float_as_uint(p[1]);
                    gv2[it].x = __float_as_uint(p[2]); gv2[it].y = __float_as_uint(p[3]);
                }
            } else if (jj == 14) {
                #pragma unroll
                for (int it = 0; it < 4; ++it) {
                    const float* p = p2emb + p2S[sn * LSEQ + l0 + it * 32] * POS;
                    gv[it].x  = __float_as_uint(p[0]); gv[it].y  = __float_as_uint(p[1]);
                    gv2[it].x = __float_as_uint(p[2]); gv2[it].y = __float_as_uint(p[3]);
                }
            } else {
                #pragma unroll
                for (int it = 0; it < 4; ++it) {
                    int li = sn * LSEQ + l0 + it * 32;
                    gv[it].x = __float_as_uint(p1emb[p1S[li] * POS + 4]);
                    gv[it].y = __float_as_uint(p2emb[p2S[li] * POS + 4]);
                }
            }
        }
        __builtin_amdgcn_sched_barrier(0);

        // ---- compute current sentence (all gather vmcnt waits migrate past this)
        compute_one_lds(embS + (s & 1) * SSTR, Bw, m, quad, nt0, lane,
                        conv_b, &hS[s][0]);
        __builtin_amdgcn_sched_barrier(0);

        // ---- phase W: convert pos lanes now (loads landed), write everything
        if (do_g) {
            unsigned short* slab = embS + (sn & 1) * SSTR;
            int off = (jj < 13) ? jj * 4 : 52 + (jj - 13) * 4;
            #pragma unroll
            for (int it = 0; it < 4; ++it) {
                uint2 v;
                if (jj < 13) {
                    v = gv[it];
                } else if (jj == 15) {
                    v.x = pk(__uint_as_float(gv[it].x), 0.f);
                    v.y = pk(__uint_as_float(gv[it].y), 0.f);
                } else {
                    v.x = pk(__uint_as_float(gv[it].x),  __uint_as_float(gv[it].y));
                    v.y = pk(__uint_as_float(gv2[it].x), __uint_as_float(gv2[it].y));
                }
                int l = l0 + it * 32;
                *(uint2*)(slab + (l + 1) * ESTR + off) = v;
            }
        }
        __syncthreads();
    }

    // ---- bag attention (wave s computes logit of sentence s)
    const int start = scope[2 * b];
    int ns = scope[2 * b + 1] - start;
    if (ns > BAGSZ) ns = BAGSZ;
    const int rel = relation[b];
    {
        float t = 0.f;
        #pragma unroll
        for (int k = 0; k < 4; ++k) {
            int c = lane + 64 * k;
            t += (c < HIDD) ? hS[wave][c] * rel_w[rel * HIDD + c] : 0.f;
        }
        #pragma unroll
        for (int off = 32; off > 0; off >>= 1) t += __shfl_xor(t, off);
        if (lane == 0) lgS[wave] = t;
    }
    __syncthreads();

    float mx = -1e30f;
    #pragma unroll
    for (int s = 0; s < BAGSZ; ++s) if (s < ns) mx = fmaxf(mx, lgS[s]);
    float aw[BAGSZ]; float den = 0.f;
    #pragma unroll
    for (int s = 0; s < BAGSZ; ++s) { aw[s] = (s < ns) ? expf(lgS[s] - mx) : 0.f; den += aw[s]; }
    float inv = 1.f / den;
    if (tid < HIDD) {
        float r = 0.f;
        #pragma unroll
        for (int s = 0; s < BAGSZ; ++s) r += aw[s] * hS[s][tid];
        repS[tid] = r * inv;
    }
    __syncthreads();

    // ---- classifier: wave w handles relations w, w+8, w+16, w+24
    #pragma unroll 1
    for (int g = wave; g < NREL; g += 8) {
        float t = 0.f;
        #pragma unroll
        for (int k = 0; k < 4; ++k) {
            int c = lane + 64 * k;
            t += (c < HIDD) ? repS[c] * rel_w[g * HIDD + c] : 0.f;
        }
        #pragma unroll
        for (int off = 32; off > 0; off >>= 1) t += __shfl_xor(t, off);
        if (lane == 0) out[b * NREL + g] = t + rel_b[g];
    }
}

// ---- fallback: the proven round-0 fused encoder with f32 wemb (verbatim) ----
__global__ __launch_bounds__(512, 4) void encoder_f32(
    const int*   __restrict__ X,  const int* __restrict__ P1, const int* __restrict__ P2,
    const float* __restrict__ wemb, const float* __restrict__ p1emb, const float* __restrict__ p2emb,
    const unsigned short* __restrict__ Bfrag, const float* __restrict__ conv_b,
    float* __restrict__ H)
{
    __shared__ unsigned short embS[2 * SSTR];
    __shared__ int xS[2 * LSEQ], p1S[2 * LSEQ], p2S[2 * LSEQ];
    const int b2 = blockIdx.x * 2, tid = threadIdx.x;
    const int lane = tid & 63;
    const int wave = __builtin_amdgcn_readfirstlane(tid >> 6);
    const int nt0  = wave * 2;
    const int m    = lane & 15;
    const int quad = lane >> 4;

    short8 Bw[2][KSTEPS];
    #pragma unroll
    for (int t = 0; t < 2; ++t)
        #pragma unroll
        for (int ks = 0; ks < KSTEPS; ++ks)
            Bw[t][ks] = *(const short8*)(Bfrag + ((size_t)((nt0 + t) * KSTEPS + ks) * 64 + lane) * 8);

    #pragma unroll
    for (int it = 0; it < 2; ++it) {
        int i = tid + it * 512;
        if (i < 768) {
            int which = i >> 8, l2 = i & 255;
            const int* src = (which == 0) ? X : (which == 1) ? P1 : P2;
            int v = src[(size_t)b2 * LSEQ + l2];
            int* dst = (which == 0) ? xS : (which == 1) ? p1S : p2S;
            dst[l2] = v;
        } else {
            int t = i - 768;
            if (t < 128) {
                int sent = t >> 6;
                int r = (t & 32) ? (SLOTS - 1) : 0;
                *(unsigned*)(embS + sent * SSTR + r * ESTR + (t & 31) * 2) = 0u;
            }
        }
    }
    __syncthreads();

    #pragma unroll
    for (int it = 0; it < (2 * LSEQ * 16) / 512; ++it) {
        int i = tid + it * 512;
        int sent = i >> 11, rem = i & 2047;
        int l = rem >> 4, j = rem & 15;
        int li = sent * LSEQ + l;
        unsigned short* dst = embS + sent * SSTR + (l + 1) * ESTR;
        uint2 v;
        if (j < 13) {
            const float* src = wemb + (size_t)xS[li] * VEC + j * 4;
            float2 fa = *(const float2*)(src);
            float a2 = 0.f, a3 = 0.f;
            if (j < 12) { float2 fb = *(const float2*)(src + 2); a2 = fb.x; a3 = fb.y; }
            v.x = pk(fa.x, fa.y); v.y = pk(a2, a3);
        } else if (j == 13) {
            const float* p = p1emb + p1S[li] * POS;
            v.x = pk(p[0], p[1]); v.y = pk(p[2], p[3]);
        } else if (j == 14) {
            const float* p = p2emb + p2S[li] * POS;
            v.x = pk(p[0], p[1]); v.y = pk(p[2], p[3]);
        } else {
            float a = p1emb[p1S[li] * POS + 4];
            float b = p2emb[p2S[li] * POS + 4];
            v.x = pk(a, 0.f); v.y = pk(b, 0.f);
        }
        *(uint2*)(dst + (j < 13 ? j * 4 : 52 + (j - 13) * 4)) = v;
    }
    __syncthreads();

    #pragma unroll 1
    for (int s = 0; s < 2; ++s) {
        const unsigned short* eb = embS + s * SSTR;
        float maxv[2][4];
        #pragma unroll
        for (int t = 0; t < 2; ++t)
            #pragma unroll
            for (int r = 0; r < 4; ++r) maxv[t][r] = -1e30f;

        #pragma unroll
        for (int mt = 0; mt < 8; ++mt) {
            short8 A[KSTEPS];
            #pragma unroll
            for (int ks = 0; ks < KSTEPS; ++ks) {
                int tap = ks >> 1;
                int col = (ks & 1) * 32 + quad * 8;
                int row = mt * 16 + m + tap;
                A[ks] = *(const short8*)(eb + row * ESTR + col);
            }
            f32x4 acc[2];
            #pragma unroll
            for (int t = 0; t < 2; ++t) acc[t] = (f32x4){0.f, 0.f, 0.f, 0.f};
            #pragma unroll
            for (int ks = 0; ks < KSTEPS; ++ks)
                #pragma unroll
                for (int t = 0; t < 2; ++t)
                    acc[t] = __builtin_amdgcn_mfma_f32_16x16x32_bf16(A[ks], Bw[t][ks], acc[t], 0, 0, 0);
            #pragma unroll
            for (int t = 0; t < 2; ++t)
                #pragma unroll
                for (int r = 0; r < 4; ++r)
                    maxv[t][r] = fmaxf(maxv[t][r], acc[t][r]);
        }

        #pragma unroll
        for (int t = 0; t < 2; ++t) {
            float v = fmaxf(fmaxf(maxv[t][0], maxv[t][1]),
                            fmaxf(maxv[t][2], maxv[t][3]));
            v = fmaxf(v, __shfl_xor(v, 16));
            v = fmaxf(v, __shfl_xor(v, 32));
            int c = (nt0 + t) * 16 + lane;
            if (lane < 16 && c < HIDD)
                H[(size_t)(b2 + s) * HSTR + c] = fmaxf(v + conv_b[c], 0.f);
        }
    }
}

// ---- fallback attn: one wave per bag (verbatim) ----
__global__ __launch_bounds__(64) void attn(
    const float* __restrict__ H, const float* __restrict__ rel_w, const float* __restrict__ rel_b,
    const int* __restrict__ relation, const int* __restrict__ scope,
    float* __restrict__ out)
{
    const int b = blockIdx.x, lane = threadIdx.x;
    const int start = scope[2 * b];
    int ns = scope[2 * b + 1] - start;
    if (ns > 8) ns = 8;
    const int rel = relation[b];

    float q[4], h[8][4];
    #pragma unroll
    for (int k = 0; k < 4; ++k) {
        int c = lane + 64 * k;
        q[k] = (c < HIDD) ? rel_w[rel * HIDD + c] : 0.f;
    }
    #pragma unroll
    for (int s = 0; s < 8; ++s)
        #pragma unroll
        for (int k = 0; k < 4; ++k) {
            int c = lane + 64 * k;
            h[s][k] = (s < ns && c < HIDD) ? H[(size_t)(start + s) * HSTR + c] : 0.f;
        }

    float logit[8];
    #pragma unroll
    for (int s = 0; s < 8; ++s) {
        float t = q[0] * h[s][0] + q[1] * h[s][1] + q[2] * h[s][2] + q[3] * h[s][3];
        #pragma unroll
        for (int off = 32; off > 0; off >>= 1) t += __shfl_xor(t, off);
        logit[s] = t;
    }

    float mx = -1e30f;
    for (int s = 0; s < ns; ++s) mx = fmaxf(mx, logit[s]);
    float a[8], den = 0.f;
    #pragma unroll
    for (int s = 0; s < 8; ++s) { a[s] = (s < ns) ? expf(logit[s] - mx) : 0.f; den += a[s]; }
    float inv = 1.f / den;

    float rep[4];
    #pragma unroll
    for (int k = 0; k < 4; ++k) {
        float r = 0.f;
        #pragma unroll
        for (int s = 0; s < 8; ++s) r += a[s] * h[s][k];
        rep[k] = r * inv;
    }

    #pragma unroll 5
    for (int g = 0; g < NREL; ++g) {
        float t = 0.f;
        #pragma unroll
        for (int k = 0; k < 4; ++k) {
            int c = lane + 64 * k;
            t += (c < HIDD) ? rel_w[g * HIDD + c] * rep[k] : 0.f;
        }
        #pragma unroll
        for (int off = 32; off > 0; off >>= 1) t += __shfl_xor(t, off);
        if (lane == 0) out[b * NREL + g] = t + rel_b[g];
    }
}

extern "C" void kernel_launch(void* const* d_in, const int* in_sizes, int n_in,
                              void* d_out, int out_size, void* d_ws, size_t ws_size,
                              hipStream_t stream) {
    const int*   X        = (const int*)d_in[0];
    const int*   P1       = (const int*)d_in[1];
    const int*   P2       = (const int*)d_in[2];
    const int*   scope    = (const int*)d_in[5];
    const int*   relation = (const int*)d_in[6];
    const float* wemb     = (const float*)d_in[7];
    const float* p1emb    = (const float*)d_in[8];
    const float* p2emb    = (const float*)d_in[9];
    const float* conv_w   = (const float*)d_in[10];
    const float* conv_b   = (const float*)d_in[11];
    const float* rel_w    = (const float*)d_in[12];
    const float* rel_b    = (const float*)d_in[13];

    // workspace layout
    char* ws = (char*)d_ws;
    float* H = (float*)ws;                                   // 4000*232*4 (fallback only)
    const size_t offB = (size_t)NSENT * HSTR * 4;
    unsigned short* Bfrag = (unsigned short*)(ws + offB);    // 16*6*64*8*2 = 98,304
    const size_t offW = offB + (size_t)NTILEP * KSTEPS * 64 * 8 * 2;
    unsigned short* wbf = (unsigned short*)(ws + offW);      // 50002*52*2 = 5,200,208
    const size_t need = offW + (size_t)NVOCAB * WSTR * 2;

    if (ws_size >= need) {
        // merged prep: wbf cvt (2540 blocks) + Bfrag build (192 blocks)
        hipLaunchKernelGGL(prep, dim3(WBLOCKS + 192), dim3(256), 0, stream,
                           conv_w, wemb, Bfrag, wbf);
        // one block = one bag: encoder pipeline + fused attention/classifier
        hipLaunchKernelGGL(encoder_bag, dim3(NBAG), dim3(512), 0, stream,
                           X, P1, P2, wbf, p1emb, p2emb, Bfrag, conv_b,
                           relation, scope, rel_w, rel_b, (float*)d_out);
    } else {
        const int btot = NTILEP * KSTEPS * 64 * 8;
        hipLaunchKernelGGL(prep_b, dim3((btot + 255) / 256), dim3(256), 0, stream,
                           conv_w, Bfrag);
        hipLaunchKernelGGL(encoder_f32, dim3(NSENT / 2), dim3(512), 0, stream,
                           X, P1, P2, wemb, p1emb, p2emb, Bfrag, conv_b, H);
        hipLaunchKernelGGL(attn, dim3(NBAG), dim3(64), 0, stream,
                           H, rel_w, rel_b, relation, scope, (float*)d_out);
    }
}

// Round 11
// 149.926 us; speedup vs baseline: 1.1234x; 1.1234x over previous
//
#include <hip/hip_runtime.h>
#include <hip/hip_bf16.h>

#define NSENT 4000
#define LSEQ  128
#define VEC   50
#define WSTR  52      // bf16 word-emb row stride (shorts): 50 real + 2 zero, 104 B (8B-aligned)
#define NVOCAB 50002
#define POS   5
#define EMBD  60      // VEC + 2*POS
#define HIDD  230
#define HSTR  232     // padded channel stride for H / hS
#define NBAG  500
#define NREL  25
#define BAGSZ 8
#define NTILEP 16     // padded N-tile count (15 real, tile 15 = zeros)
#define KSTEPS 6      // K = 192 (3 taps * 64 e-slots), 6 MFMA K-steps of 32
#define ESTR  72      // LDS row stride in bf16 shorts (144 B)
#define SLOTS 130     // l+1 shift; rows 0/129 are SAME-pad zeros
#define SSTR  (SLOTS * ESTR)   // per-sentence LDS slab (shorts)
#define WBLOCKS 2540  // prep: wbf part = NVOCAB*13 uint2-threads / 256

// e-slot mapping (A and B MUST agree):
//   e 0..49  = wemb dims 0..49      (e50,51 = 0)
//   e 52..55 = p1 dims 0..3
//   e 56..59 = p2 dims 0..3
//   e 60     = p1 dim 4, e61 = 0
//   e 62     = p2 dim 4, e63 = 0
typedef __attribute__((ext_vector_type(8))) short short8;   // 8 bf16 = 4 VGPRs
typedef __attribute__((ext_vector_type(4))) float f32x4;

__device__ __forceinline__ unsigned short f2bf(float f) {
    union { float f; unsigned u; } v; v.f = f;
    unsigned u = v.u + 0x7FFF + ((v.u >> 16) & 1);   // RNE
    return (unsigned short)(u >> 16);
}

// packed f32x2 -> bf16x2 (v_cvt_pk_bf16_f32 on gfx950), low short = first arg
__device__ __forceinline__ unsigned pk(float a, float b) {
    __hip_bfloat162 h = __float22bfloat162_rn(float2{a, b});
    union { __hip_bfloat162 h; unsigned u; } c; c.h = h;
    return c.u;
}

// ---- merged prep: wbf table cvt (blocks < WBLOCKS) + Bfrag build (rest) ----
__global__ __launch_bounds__(256) void prep(const float* __restrict__ conv_w,
                                            const float* __restrict__ wemb,
                                            unsigned short* __restrict__ Bfrag,
                                            unsigned short* __restrict__ wbf) {
    int bid = blockIdx.x;
    if (bid < WBLOCKS) {
        int idx = bid * 256 + threadIdx.x;        // one uint2 (4 shorts) of wbf
        if (idx < NVOCAB * 13) {
            int r = idx / 13, cj = (idx % 13) * 4;
            const float* src = wemb + (size_t)r * VEC + cj;
            float2 a = *(const float2*)src;
            float2 b = (cj < 48) ? *(const float2*)(src + 2) : float2{0.f, 0.f};
            uint2 v; v.x = pk(a.x, a.y); v.y = pk(b.x, b.y);
            *(uint2*)(wbf + (size_t)r * WSTR + cj) = v;
        }
    } else {
        int idx = (bid - WBLOCKS) * 256 + threadIdx.x;
        if (idx >= NTILEP * KSTEPS * 64 * 8) return;
        int j    = idx & 7;
        int lane = (idx >> 3) & 63;
        int t    = idx >> 9;
        int ks   = t % KSTEPS;
        int nt   = t / KSTEPS;
        int c    = nt * 16 + (lane & 15);
        int klin = ks * 32 + (lane >> 4) * 8 + j;
        int tap  = klin >> 6;
        int e    = klin & 63;
        float v  = 0.f;
        if (c < HIDD) {
            int eidx = -1;
            if (e < 50)                 eidx = e;             // wemb dims
            else if (e >= 52 && e < 56) eidx = 50 + (e - 52); // p1[0..3]
            else if (e >= 56 && e < 60) eidx = 55 + (e - 56); // p2[0..3]
            else if (e == 60)           eidx = 54;            // p1[4]
            else if (e == 62)           eidx = 59;            // p2[4]
            if (eidx >= 0) v = conv_w[(c * EMBD + eidx) * 3 + tap];
        }
        Bfrag[idx] = f2bf(v);
    }
}

// ---- standalone prep_b for the fallback path (no wbf region in ws) ----
__global__ __launch_bounds__(256) void prep_b(const float* __restrict__ conv_w,
                                              unsigned short* __restrict__ Bfrag) {
    int idx = blockIdx.x * 256 + threadIdx.x;
    if (idx >= NTILEP * KSTEPS * 64 * 8) return;
    int j    = idx & 7;
    int lane = (idx >> 3) & 63;
    int t    = idx >> 9;
    int ks   = t % KSTEPS;
    int nt   = t / KSTEPS;
    int c    = nt * 16 + (lane & 15);
    int klin = ks * 32 + (lane >> 4) * 8 + j;
    int tap  = klin >> 6;
    int e    = klin & 63;
    float v  = 0.f;
    if (c < HIDD) {
        int eidx = -1;
        if (e < 50)                 eidx = e;
        else if (e >= 52 && e < 56) eidx = 50 + (e - 52);
        else if (e >= 56 && e < 60) eidx = 55 + (e - 56);
        else if (e == 60)           eidx = 54;
        else if (e == 62)           eidx = 59;
        if (eidx >= 0) v = conv_w[(c * EMBD + eidx) * 3 + tap];
    }
    Bfrag[idx] = f2bf(v);
}

// ---- gather one sentence (prologue only); R7-proven code ----
__device__ __forceinline__ void gather_one(
    unsigned short* __restrict__ slab, int s, int tid,
    const int* __restrict__ xS, const int* __restrict__ p1S, const int* __restrict__ p2S,
    const unsigned short* __restrict__ wbf,
    const float* __restrict__ p1emb, const float* __restrict__ p2emb)
{
    #pragma unroll
    for (int it = 0; it < (LSEQ * 16) / 512; ++it) {
        int i = tid + it * 512;
        int l = i >> 4, j = i & 15;
        int li = s * LSEQ + l;
        unsigned short* dst = slab + (l + 1) * ESTR;
        uint2 v;
        if (j < 13) {                 // shorts 4j..4j+3 of bf16 row (j=12 brings the 2 zeros)
            v = *(const uint2*)(wbf + (size_t)xS[li] * WSTR + j * 4);
        } else if (j == 13) {         // p1[0..3] -> e52..55
            const float* p = p1emb + p1S[li] * POS;
            v.x = pk(p[0], p[1]); v.y = pk(p[2], p[3]);
        } else if (j == 14) {         // p2[0..3] -> e56..59
            const float* p = p2emb + p2S[li] * POS;
            v.x = pk(p[0], p[1]); v.y = pk(p[2], p[3]);
        } else {                      // tails -> e60..63
            float a = p1emb[p1S[li] * POS + 4];
            float b = p2emb[p2S[li] * POS + 4];
            v.x = pk(a, 0.f); v.y = pk(b, 0.f);
        }
        *(uint2*)(dst + (j < 13 ? j * 4 : 52 + (j - 13) * 4)) = v;
    }
}

// ---- compute one sentence: PROVEN R5/R7 inner loop; output -> LDS hrow ----
__device__ __forceinline__ void compute_one_lds(
    const unsigned short* __restrict__ eb, const short8 Bw[2][KSTEPS],
    int m, int quad, int nt0, int lane,
    const float* __restrict__ conv_b, float* __restrict__ hrow)
{
    float maxv[2][4];
    #pragma unroll
    for (int t = 0; t < 2; ++t)
        #pragma unroll
        for (int r = 0; r < 4; ++r) maxv[t][r] = -1e30f;

    #pragma unroll
    for (int mt = 0; mt < 8; ++mt) {
        short8 A[KSTEPS];
        #pragma unroll
        for (int ks = 0; ks < KSTEPS; ++ks) {
            int tap = ks >> 1;
            int col = (ks & 1) * 32 + quad * 8;
            int row = mt * 16 + m + tap;        // slot (l+tap), +1 shift folded in
            A[ks] = *(const short8*)(eb + row * ESTR + col);
        }
        f32x4 acc[2];
        #pragma unroll
        for (int t = 0; t < 2; ++t) acc[t] = (f32x4){0.f, 0.f, 0.f, 0.f};
        #pragma unroll
        for (int ks = 0; ks < KSTEPS; ++ks)
            #pragma unroll
            for (int t = 0; t < 2; ++t)
                acc[t] = __builtin_amdgcn_mfma_f32_16x16x32_bf16(A[ks], Bw[t][ks], acc[t], 0, 0, 0);
        #pragma unroll
        for (int t = 0; t < 2; ++t)
            #pragma unroll
            for (int r = 0; r < 4; ++r)
                maxv[t][r] = fmaxf(maxv[t][r], acc[t][r]);
    }

    #pragma unroll
    for (int t = 0; t < 2; ++t) {
        float v = fmaxf(fmaxf(maxv[t][0], maxv[t][1]),
                        fmaxf(maxv[t][2], maxv[t][3]));
        v = fmaxf(v, __shfl_xor(v, 16));
        v = fmaxf(v, __shfl_xor(v, 32));
        int c = (nt0 + t) * 16 + lane;
        if (lane < 16 && c < HIDD)
            hrow[c] = fmaxf(v + conv_b[c], 0.f);
    }
}

// ---- Kernel 2: ONE BLOCK = ONE BAG, T14 split-gather pipeline (R9 PROVEN) ----
// R9 verbatim (149.2us total measured — session best). R10's attempt to move
// pos-lane pk conversions to phase W added 8 VGPRs of cross-compute liveness
// (gv2) and the allocator SPILLED to scratch at its hard 64-VGPR ceiling
// (WRITE_SIZE 13->30MB, encoder 71->87us). This allocator has now rejected
// liveness growth 4 times (R3/R6/R10 + pre-session); R9's 8 held VGPRs is
// the exact ceiling. DO NOT add state across compute_one_lds.
// Structure: per round {phase L: issue loads (pos lanes pk inline — tables
// are L1-resident, wait is short); sched_barrier; compute(s); sched_barrier;
// phase W: ds_writes}; bag attention + classifier as LDS tail.
// LDS: 37440 (2 slabs) + 12288 (idx) + 7424 (hS) + 960 (lgS/repS) = 58.1 KB.
__global__ __launch_bounds__(512, 4) void encoder_bag(
    const int*   __restrict__ X,  const int* __restrict__ P1, const int* __restrict__ P2,
    const unsigned short* __restrict__ wbf,
    const float* __restrict__ p1emb, const float* __restrict__ p2emb,
    const unsigned short* __restrict__ Bfrag, const float* __restrict__ conv_b,
    const int* __restrict__ relation, const int* __restrict__ scope,
    const float* __restrict__ rel_w, const float* __restrict__ rel_b,
    float* __restrict__ out)
{
    __shared__ unsigned short embS[2 * SSTR];            // 2 alternating slabs
    __shared__ int xS[BAGSZ * LSEQ], p1S[BAGSZ * LSEQ], p2S[BAGSZ * LSEQ];
    __shared__ float hS[BAGSZ][HSTR];                    // encoder outputs
    __shared__ float lgS[BAGSZ];                         // bag logits
    __shared__ float repS[HSTR];                         // bag representation
    const int b = blockIdx.x, tid = threadIdx.x;
    const int lane = tid & 63;
    const int wave = __builtin_amdgcn_readfirstlane(tid >> 6);
    const int nt0  = wave * 2;
    const int m    = lane & 15;
    const int quad = lane >> 4;
    const int jj   = tid & 15;     // gather column role, constant per thread
    const int l0   = tid >> 4;     // gather base token, +32 per iteration

    // ---- this wave's B fragments -> registers (48 VGPRs), issued first
    short8 Bw[2][KSTEPS];
    #pragma unroll
    for (int t = 0; t < 2; ++t)
        #pragma unroll
        for (int ks = 0; ks < KSTEPS; ++ks)
            Bw[t][ks] = *(const short8*)(Bfrag + ((size_t)((nt0 + t) * KSTEPS + ks) * 64 + lane) * 8);

    // ---- stage index rows for all 8 sentences (3072 coalesced ints)
    #pragma unroll
    for (int it = 0; it < 6; ++it) {
        int i = tid + it * 512;
        int arr = i >> 10, off = i & 1023;
        const int* src = (arr == 0) ? X : (arr == 1) ? P1 : P2;
        int v = src[(size_t)b * (BAGSZ * LSEQ) + off];
        int* dst = (arr == 0) ? xS : (arr == 1) ? p1S : p2S;
        dst[off] = v;
    }
    // ---- zero SAME-pad rows of both slabs (e-slots 0..63)
    if (tid < 128) {
        int sb = tid >> 6;
        int r = (tid & 32) ? (SLOTS - 1) : 0;
        *(unsigned*)(embS + sb * SSTR + r * ESTR + (tid & 31) * 2) = 0u;
    }
    __syncthreads();

    // ---- pipeline: gather(0); then per round: loadL(s+1); compute(s); writeW(s+1)
    gather_one(embS, 0, tid, xS, p1S, p2S, wbf, p1emb, p2emb);
    __syncthreads();

    #pragma unroll 1
    for (int s = 0; s < BAGSZ; ++s) {
        const int sn = s + 1;
        const bool do_g = (sn < BAGSZ);
        uint2 gv[4];                                   // statically indexed (unrolled)

        // ---- phase L: pos lanes first (tiny tables, cheap wait), wemb raw last
        if (do_g) {
            if (jj >= 13) {
                #pragma unroll
                for (int it = 0; it < 4; ++it) {
                    int li = sn * LSEQ + l0 + it * 32;
                    if (jj == 13) {
                        const float* p = p1emb + p1S[li] * POS;
                        gv[it].x = pk(p[0], p[1]); gv[it].y = pk(p[2], p[3]);
                    } else if (jj == 14) {
                        const float* p = p2emb + p2S[li] * POS;
                        gv[it].x = pk(p[0], p[1]); gv[it].y = pk(p[2], p[3]);
                    } else {
                        float a = p1emb[p1S[li] * POS + 4];
                        float c = p2emb[p2S[li] * POS + 4];
                        gv[it].x = pk(a, 0.f); gv[it].y = pk(c, 0.f);
                    }
                }
            } else {
                #pragma unroll
                for (int it = 0; it < 4; ++it) {
                    int li = sn * LSEQ + l0 + it * 32;
                    gv[it] = *(const uint2*)(wbf + (size_t)xS[li] * WSTR + jj * 4);
                }
            }
        }
        __builtin_amdgcn_sched_barrier(0);

        // ---- compute current sentence (vmcnt for wemb loads migrates past this)
        compute_one_lds(embS + (s & 1) * SSTR, Bw, m, quad, nt0, lane,
                        conv_b, &hS[s][0]);
        __builtin_amdgcn_sched_barrier(0);

        // ---- phase W: write held gather results into the other slab
        if (do_g) {
            unsigned short* slab = embS + (sn & 1) * SSTR;
            int off = (jj < 13) ? jj * 4 : 52 + (jj - 13) * 4;
            #pragma unroll
            for (int it = 0; it < 4; ++it) {
                int l = l0 + it * 32;
                *(uint2*)(slab + (l + 1) * ESTR + off) = gv[it];
            }
        }
        __syncthreads();
    }

    // ---- bag attention (wave s computes logit of sentence s)
    const int start = scope[2 * b];
    int ns = scope[2 * b + 1] - start;
    if (ns > BAGSZ) ns = BAGSZ;
    const int rel = relation[b];
    {
        float t = 0.f;
        #pragma unroll
        for (int k = 0; k < 4; ++k) {
            int c = lane + 64 * k;
            t += (c < HIDD) ? hS[wave][c] * rel_w[rel * HIDD + c] : 0.f;
        }
        #pragma unroll
        for (int off = 32; off > 0; off >>= 1) t += __shfl_xor(t, off);
        if (lane == 0) lgS[wave] = t;
    }
    __syncthreads();

    float mx = -1e30f;
    #pragma unroll
    for (int s = 0; s < BAGSZ; ++s) if (s < ns) mx = fmaxf(mx, lgS[s]);
    float aw[BAGSZ]; float den = 0.f;
    #pragma unroll
    for (int s = 0; s < BAGSZ; ++s) { aw[s] = (s < ns) ? expf(lgS[s] - mx) : 0.f; den += aw[s]; }
    float inv = 1.f / den;
    if (tid < HIDD) {
        float r = 0.f;
        #pragma unroll
        for (int s = 0; s < BAGSZ; ++s) r += aw[s] * hS[s][tid];
        repS[tid] = r * inv;
    }
    __syncthreads();

    // ---- classifier: wave w handles relations w, w+8, w+16, w+24
    #pragma unroll 1
    for (int g = wave; g < NREL; g += 8) {
        float t = 0.f;
        #pragma unroll
        for (int k = 0; k < 4; ++k) {
            int c = lane + 64 * k;
            t += (c < HIDD) ? repS[c] * rel_w[g * HIDD + c] : 0.f;
        }
        #pragma unroll
        for (int off = 32; off > 0; off >>= 1) t += __shfl_xor(t, off);
        if (lane == 0) out[b * NREL + g] = t + rel_b[g];
    }
}

// ---- fallback: the proven round-0 fused encoder with f32 wemb (verbatim) ----
__global__ __launch_bounds__(512, 4) void encoder_f32(
    const int*   __restrict__ X,  const int* __restrict__ P1, const int* __restrict__ P2,
    const float* __restrict__ wemb, const float* __restrict__ p1emb, const float* __restrict__ p2emb,
    const unsigned short* __restrict__ Bfrag, const float* __restrict__ conv_b,
    float* __restrict__ H)
{
    __shared__ unsigned short embS[2 * SSTR];
    __shared__ int xS[2 * LSEQ], p1S[2 * LSEQ], p2S[2 * LSEQ];
    const int b2 = blockIdx.x * 2, tid = threadIdx.x;
    const int lane = tid & 63;
    const int wave = __builtin_amdgcn_readfirstlane(tid >> 6);
    const int nt0  = wave * 2;
    const int m    = lane & 15;
    const int quad = lane >> 4;

    short8 Bw[2][KSTEPS];
    #pragma unroll
    for (int t = 0; t < 2; ++t)
        #pragma unroll
        for (int ks = 0; ks < KSTEPS; ++ks)
            Bw[t][ks] = *(const short8*)(Bfrag + ((size_t)((nt0 + t) * KSTEPS + ks) * 64 + lane) * 8);

    #pragma unroll
    for (int it = 0; it < 2; ++it) {
        int i = tid + it * 512;
        if (i < 768) {
            int which = i >> 8, l2 = i & 255;
            const int* src = (which == 0) ? X : (which == 1) ? P1 : P2;
            int v = src[(size_t)b2 * LSEQ + l2];
            int* dst = (which == 0) ? xS : (which == 1) ? p1S : p2S;
            dst[l2] = v;
        } else {
            int t = i - 768;
            if (t < 128) {
                int sent = t >> 6;
                int r = (t & 32) ? (SLOTS - 1) : 0;
                *(unsigned*)(embS + sent * SSTR + r * ESTR + (t & 31) * 2) = 0u;
            }
        }
    }
    __syncthreads();

    #pragma unroll
    for (int it = 0; it < (2 * LSEQ * 16) / 512; ++it) {
        int i = tid + it * 512;
        int sent = i >> 11, rem = i & 2047;
        int l = rem >> 4, j = rem & 15;
        int li = sent * LSEQ + l;
        unsigned short* dst = embS + sent * SSTR + (l + 1) * ESTR;
        uint2 v;
        if (j < 13) {
            const float* src = wemb + (size_t)xS[li] * VEC + j * 4;
            float2 fa = *(const float2*)(src);
            float a2 = 0.f, a3 = 0.f;
            if (j < 12) { float2 fb = *(const float2*)(src + 2); a2 = fb.x; a3 = fb.y; }
            v.x = pk(fa.x, fa.y); v.y = pk(a2, a3);
        } else if (j == 13) {
            const float* p = p1emb + p1S[li] * POS;
            v.x = pk(p[0], p[1]); v.y = pk(p[2], p[3]);
        } else if (j == 14) {
            const float* p = p2emb + p2S[li] * POS;
            v.x = pk(p[0], p[1]); v.y = pk(p[2], p[3]);
        } else {
            float a = p1emb[p1S[li] * POS + 4];
            float b = p2emb[p2S[li] * POS + 4];
            v.x = pk(a, 0.f); v.y = pk(b, 0.f);
        }
        *(uint2*)(dst + (j < 13 ? j * 4 : 52 + (j - 13) * 4)) = v;
    }
    __syncthreads();

    #pragma unroll 1
    for (int s = 0; s < 2; ++s) {
        const unsigned short* eb = embS + s * SSTR;
        float maxv[2][4];
        #pragma unroll
        for (int t = 0; t < 2; ++t)
            #pragma unroll
            for (int r = 0; r < 4; ++r) maxv[t][r] = -1e30f;

        #pragma unroll
        for (int mt = 0; mt < 8; ++mt) {
            short8 A[KSTEPS];
            #pragma unroll
            for (int ks = 0; ks < KSTEPS; ++ks) {
                int tap = ks >> 1;
                int col = (ks & 1) * 32 + quad * 8;
                int row = mt * 16 + m + tap;
                A[ks] = *(const short8*)(eb + row * ESTR + col);
            }
            f32x4 acc[2];
            #pragma unroll
            for (int t = 0; t < 2; ++t) acc[t] = (f32x4){0.f, 0.f, 0.f, 0.f};
            #pragma unroll
            for (int ks = 0; ks < KSTEPS; ++ks)
                #pragma unroll
                for (int t = 0; t < 2; ++t)
                    acc[t] = __builtin_amdgcn_mfma_f32_16x16x32_bf16(A[ks], Bw[t][ks], acc[t], 0, 0, 0);
            #pragma unroll
            for (int t = 0; t < 2; ++t)
                #pragma unroll
                for (int r = 0; r < 4; ++r)
                    maxv[t][r] = fmaxf(maxv[t][r], acc[t][r]);
        }

        #pragma unroll
        for (int t = 0; t < 2; ++t) {
            float v = fmaxf(fmaxf(maxv[t][0], maxv[t][1]),
                            fmaxf(maxv[t][2], maxv[t][3]));
            v = fmaxf(v, __shfl_xor(v, 16));
            v = fmaxf(v, __shfl_xor(v, 32));
            int c = (nt0 + t) * 16 + lane;
            if (lane < 16 && c < HIDD)
                H[(size_t)(b2 + s) * HSTR + c] = fmaxf(v + conv_b[c], 0.f);
        }
    }
}

// ---- fallback attn: one wave per bag (verbatim) ----
__global__ __launch_bounds__(64) void attn(
    const float* __restrict__ H, const float* __restrict__ rel_w, const float* __restrict__ rel_b,
    const int* __restrict__ relation, const int* __restrict__ scope,
    float* __restrict__ out)
{
    const int b = blockIdx.x, lane = threadIdx.x;
    const int start = scope[2 * b];
    int ns = scope[2 * b + 1] - start;
    if (ns > 8) ns = 8;
    const int rel = relation[b];

    float q[4], h[8][4];
    #pragma unroll
    for (int k = 0; k < 4; ++k) {
        int c = lane + 64 * k;
        q[k] = (c < HIDD) ? rel_w[rel * HIDD + c] : 0.f;
    }
    #pragma unroll
    for (int s = 0; s < 8; ++s)
        #pragma unroll
        for (int k = 0; k < 4; ++k) {
            int c = lane + 64 * k;
            h[s][k] = (s < ns && c < HIDD) ? H[(size_t)(start + s) * HSTR + c] : 0.f;
        }

    float logit[8];
    #pragma unroll
    for (int s = 0; s < 8; ++s) {
        float t = q[0] * h[s][0] + q[1] * h[s][1] + q[2] * h[s][2] + q[3] * h[s][3];
        #pragma unroll
        for (int off = 32; off > 0; off >>= 1) t += __shfl_xor(t, off);
        logit[s] = t;
    }

    float mx = -1e30f;
    for (int s = 0; s < ns; ++s) mx = fmaxf(mx, logit[s]);
    float a[8], den = 0.f;
    #pragma unroll
    for (int s = 0; s < 8; ++s) { a[s] = (s < ns) ? expf(logit[s] - mx) : 0.f; den += a[s]; }
    float inv = 1.f / den;

    float rep[4];
    #pragma unroll
    for (int k = 0; k < 4; ++k) {
        float r = 0.f;
        #pragma unroll
        for (int s = 0; s < 8; ++s) r += a[s] * h[s][k];
        rep[k] = r * inv;
    }

    #pragma unroll 5
    for (int g = 0; g < NREL; ++g) {
        float t = 0.f;
        #pragma unroll
        for (int k = 0; k < 4; ++k) {
            int c = lane + 64 * k;
            t += (c < HIDD) ? rel_w[g * HIDD + c] * rep[k] : 0.f;
        }
        #pragma unroll
        for (int off = 32; off > 0; off >>= 1) t += __shfl_xor(t, off);
        if (lane == 0) out[b * NREL + g] = t + rel_b[g];
    }
}

extern "C" void kernel_launch(void* const* d_in, const int* in_sizes, int n_in,
                              void* d_out, int out_size, void* d_ws, size_t ws_size,
                              hipStream_t stream) {
    const int*   X        = (const int*)d_in[0];
    const int*   P1       = (const int*)d_in[1];
    const int*   P2       = (const int*)d_in[2];
    const int*   scope    = (const int*)d_in[5];
    const int*   relation = (const int*)d_in[6];
    const float* wemb     = (const float*)d_in[7];
    const float* p1emb    = (const float*)d_in[8];
    const float* p2emb    = (const float*)d_in[9];
    const float* conv_w   = (const float*)d_in[10];
    const float* conv_b   = (const float*)d_in[11];
    const float* rel_w    = (const float*)d_in[12];
    const float* rel_b    = (const float*)d_in[13];

    // workspace layout
    char* ws = (char*)d_ws;
    float* H = (float*)ws;                                   // 4000*232*4 (fallback only)
    const size_t offB = (size_t)NSENT * HSTR * 4;
    unsigned short* Bfrag = (unsigned short*)(ws + offB);    // 16*6*64*8*2 = 98,304
    const size_t offW = offB + (size_t)NTILEP * KSTEPS * 64 * 8 * 2;
    unsigned short* wbf = (unsigned short*)(ws + offW);      // 50002*52*2 = 5,200,208
    const size_t need = offW + (size_t)NVOCAB * WSTR * 2;

    if (ws_size >= need) {
        // merged prep: wbf cvt (2540 blocks) + Bfrag build (192 blocks)
        hipLaunchKernelGGL(prep, dim3(WBLOCKS + 192), dim3(256), 0, stream,
                           conv_w, wemb, Bfrag, wbf);
        // one block = one bag: encoder pipeline + fused attention/classifier
        hipLaunchKernelGGL(encoder_bag, dim3(NBAG), dim3(512), 0, stream,
                           X, P1, P2, wbf, p1emb, p2emb, Bfrag, conv_b,
                           relation, scope, rel_w, rel_b, (float*)d_out);
    } else {
        const int btot = NTILEP * KSTEPS * 64 * 8;
        hipLaunchKernelGGL(prep_b, dim3((btot + 255) / 256), dim3(256), 0, stream,
                           conv_w, Bfrag);
        hipLaunchKernelGGL(encoder_f32, dim3(NSENT / 2), dim3(512), 0, stream,
                           X, P1, P2, wemb, p1emb, p2emb, Bfrag, conv_b, H);
        hipLaunchKernelGGL(attn, dim3(NBAG), dim3(64), 0, stream,
                           H, rel_w, rel_b, relation, scope, (float*)d_out);
    }
}